// Round 3
// baseline (10460.677 us; speedup 1.0000x reference)
//
#include <hip/hip_runtime.h>
#include <hip/hip_bf16.h>
#include <stdint.h>

// Problem dims
#define B_   16
#define T_   4096
#define F_   47
#define HID_ 64
#define CH_  256
#define TG_  1024   // T/4
#define G3_  768    // 3*CH

using bf16x8 = __attribute__((ext_vector_type(8))) short;  // 8 bf16 (4 VGPRs)
using f32x4  = __attribute__((ext_vector_type(4))) float;  // 4 fp32 acc

__device__ __forceinline__ short f2bf(float f) {
    union { float f; uint32_t u; } v; v.f = f;
    uint32_t u = v.u;
    uint32_t r = (u + 0x7fffu + ((u >> 16) & 1u)) >> 16;   // RNE
    return (short)r;
}
__device__ __forceinline__ float bf2f(short s) {
    union { uint32_t u; float f; } v; v.u = ((uint32_t)(uint16_t)s) << 16;
    return v.f;
}
__device__ __forceinline__ float fast_tanh(float x) {
    float e = __expf(2.f * x);           // inf-safe
    return 1.f - 2.f / (e + 1.f);
}
__device__ __forceinline__ float fast_sigmoid(float x) {
    return 1.f / (1.f + __expf(-x));
}

// ---------------------------------------------------------------------------
// K1: conv1 (pointwise 47->64) + tanh, fp32 VALU, writes c1 as bf16
__global__ __launch_bounds__(256) void k1_conv1(const float* __restrict__ feat,
        const float* __restrict__ W1, const float* __restrict__ b1,
        short* __restrict__ c1) {
    __shared__ float sW[47 * 64];
    __shared__ float sF[4 * 47];
    int tid = threadIdx.x;
    int b = blockIdx.x >> 10, t0 = (blockIdx.x & 1023) * 4;
    if (tid < 188) sF[tid] = feat[((size_t)b * T_ + t0) * 47 + tid];
    for (int i = tid; i < 47 * 64; i += 256) {
        int f = i >> 6, h = i & 63;
        sW[i] = W1[h * 47 + f];
    }
    __syncthreads();
    int fr = tid >> 6, h = tid & 63;
    float acc = b1[h];
    #pragma unroll
    for (int f = 0; f < 47; ++f)
        acc += sF[fr * 47 + f] * sW[f * 64 + h];
    c1[((size_t)b * T_ + t0 + fr) * 64 + h] = f2bf(fast_tanh(acc));
}

// ---------------------------------------------------------------------------
// Weight prep (bf16 B^T layouts)
__global__ __launch_bounds__(256) void k_prep(const float* __restrict__ W2,
        const float* __restrict__ Wt, const float* __restrict__ Wih_f,
        short* __restrict__ W2t, short* __restrict__ Wtt, short* __restrict__ Wih) {
    int idx = blockIdx.x * 256 + threadIdx.x;
    if (idx < 256 * 512) {
        int o = idx >> 9, i = idx & 511, d = i >> 8, jj = i & 255;
        W2t[idx] = f2bf(W2[(size_t)o * 512 + jj * 2 + d]);
    }
    {
        int n = idx >> 8, ic = idx & 255, o = n & 255, kp = n >> 8;
        Wtt[idx] = f2bf(Wt[(size_t)ic * 1024 + o * 4 + kp]);
    }
    if (idx < G3_ * CH_)
        Wih[idx] = f2bf(Wih_f[idx]);
}

// ---------------------------------------------------------------------------
// K2: conv2 (k=2 causal) as GEMM M=16384,K=512,N=256 + tanh.
__global__ __launch_bounds__(256) void k2_conv2(const short* __restrict__ c1,
        const short* __restrict__ W2t, const float* __restrict__ b2,
        short* __restrict__ y2) {
    int tid = threadIdx.x, w = tid >> 6, l = tid & 63;
    int lane16 = l & 15, quad = l >> 4;
    int mt = blockIdx.x * 4 + w;
    int row = mt * 16 + lane16;
    int tg = row & 1023;
    const short* Arow = c1 + (size_t)row * 256 - 256;
    bf16x8 zero8 = {0,0,0,0,0,0,0,0};
    bf16x8 af[16];
    #pragma unroll
    for (int kt = 0; kt < 16; ++kt) {
        int i0 = kt * 32 + quad * 8;
        bool masked = (tg == 0) && (kt < 8);
        const short* p = masked ? c1 : (Arow + i0);
        bf16x8 v = *(const bf16x8*)p;
        af[kt] = masked ? zero8 : v;
    }
    #pragma unroll
    for (int nt = 0; nt < 16; ++nt) {
        int n = nt * 16 + lane16;
        f32x4 acc = {0.f, 0.f, 0.f, 0.f};
        const short* Brow = W2t + (size_t)n * 512 + quad * 8;
        #pragma unroll
        for (int kt = 0; kt < 16; ++kt) {
            bf16x8 bf = *(const bf16x8*)(Brow + kt * 32);
            acc = __builtin_amdgcn_mfma_f32_16x16x32_bf16(af[kt], bf, acc, 0, 0, 0);
        }
        float bias = b2[n];
        #pragma unroll
        for (int r = 0; r < 4; ++r) {
            int mrow = mt * 16 + quad * 4 + r;
            y2[(size_t)mrow * 256 + n] = f2bf(fast_tanh(acc[r] + bias));
        }
    }
}

// ---------------------------------------------------------------------------
// K3a: tconv as GEMM M=16384,K=256,N=1024 + tanh -> c3 bf16.
__global__ __launch_bounds__(256) void k3a_tconv(const short* __restrict__ y2,
        const short* __restrict__ Wtt, const float* __restrict__ bt,
        short* __restrict__ c3) {
    int tid = threadIdx.x, w = tid >> 6, l = tid & 63;
    int lane16 = l & 15, quad = l >> 4;
    int mt = blockIdx.x;
    int row = mt * 16 + lane16;
    const short* Arow = y2 + (size_t)row * 256 + quad * 8;
    bf16x8 af[8];
    #pragma unroll
    for (int kt = 0; kt < 8; ++kt) af[kt] = *(const bf16x8*)(Arow + kt * 32);
    #pragma unroll
    for (int nt2 = 0; nt2 < 16; ++nt2) {
        int n = (w * 16 + nt2) * 16 + lane16;
        f32x4 acc = {0.f, 0.f, 0.f, 0.f};
        const short* Brow = Wtt + (size_t)n * 256 + quad * 8;
        #pragma unroll
        for (int kt = 0; kt < 8; ++kt) {
            bf16x8 bf = *(const bf16x8*)(Brow + kt * 32);
            acc = __builtin_amdgcn_mfma_f32_16x16x32_bf16(af[kt], bf, acc, 0, 0, 0);
        }
        int kp = n >> 8, o = n & 255;
        float bias = bt[o];
        #pragma unroll
        for (int r = 0; r < 4; ++r) {
            int mrow = mt * 16 + quad * 4 + r;
            int bb = mrow >> 10, tgg = mrow & 1023;
            c3[(((size_t)bb * TG_ + tgg) * 4 + kp) * 256 + o] =
                f2bf(fast_tanh(acc[r] + bias));
        }
    }
}

// ---------------------------------------------------------------------------
// K3b: x-projection GEMM M=65536,K=256,N=768 (+b_ih) -> gslice bf16.
// gslice layout: [j][s][b][gate*64+cc], j = slice (n&255)>>6 — so k4 block j
// streams 3072 contiguous shorts per step.
__global__ __launch_bounds__(256) void k3b_xproj(const short* __restrict__ c3,
        const short* __restrict__ Wih, const float* __restrict__ b_ih,
        short* __restrict__ gslice) {
    int tid = threadIdx.x, w = tid >> 6, l = tid & 63;
    int lane16 = l & 15, quad = l >> 4;
    int mt = blockIdx.x;
    int row = mt * 16 + lane16;
    const short* Arow = c3 + (size_t)row * 256 + quad * 8;
    bf16x8 af[8];
    #pragma unroll
    for (int kt = 0; kt < 8; ++kt) af[kt] = *(const bf16x8*)(Arow + kt * 32);
    #pragma unroll
    for (int nt2 = 0; nt2 < 12; ++nt2) {
        int n = (w * 12 + nt2) * 16 + lane16;
        f32x4 acc = {0.f, 0.f, 0.f, 0.f};
        const short* Brow = Wih + (size_t)n * 256 + quad * 8;
        #pragma unroll
        for (int kt = 0; kt < 8; ++kt) {
            bf16x8 bf = *(const bf16x8*)(Brow + kt * 32);
            acc = __builtin_amdgcn_mfma_f32_16x16x32_bf16(af[kt], bf, acc, 0, 0, 0);
        }
        float bias = b_ih[n];
        int gate = n >> 8, rem = n & 255, jj = rem >> 6, cc = rem & 63;
        #pragma unroll
        for (int r = 0; r < 4; ++r) {
            int mrow = mt * 16 + quad * 4 + r;
            int bb = mrow >> 12, s = mrow & 4095;
            gslice[(((size_t)jj * T_ + s) * 16 + bb) * 192 + gate * 64 + cc] =
                f2bf(acc[r] + bias);
        }
    }
}

// ---------------------------------------------------------------------------
// K_zero: zero the k4 progress flags (ws poisoned 0xAA). Runs after k3b.
__global__ __launch_bounds__(128) void k_zero(int* __restrict__ prog) {
    prog[threadIdx.x] = 0;   // 128 ints (4 blocks x 32-int stride)
}

// ---------------------------------------------------------------------------
// K4: batch-consolidated GRU, 4 blocks x 512 thr. All 16 batches in MFMA M;
// N=768 sliced 4 ways (block j owns channels j*64..j*64+63 of each gate =
// 12 N-tiles). Per step per CU: 96 MFMAs (466 cyc) vs 384 before.
// Cross-block h exchange each step via agent-scope atomics (Hx + prog flags),
// own-chunk K-tiles of next step's matvec overlapped with the spin.
__global__ __launch_bounds__(512) void k4_gru_x4(const float* __restrict__ W_hh,
        const float* __restrict__ b_hh, const short* __restrict__ gslice,
        float* __restrict__ out, uint32_t* __restrict__ Hx, int* __restrict__ prog) {
    __shared__ __align__(16) short h_all[16 * 264];      // padded: bank-spread
    __shared__ float gh_s[16 * 193];                     // odd stride: bank-spread
    __shared__ __align__(16) short gxr[4 * 3072];        // 4-step gate ring
    __shared__ __align__(16) float ob[4 * 1024];         // out staging

    int tid = threadIdx.x, l = tid & 63, w = tid >> 6;
    int lane16 = l & 15, quad = l >> 4;
    int j = blockIdx.x;
    bool w4 = (w < 4);

    // ---- W_hh register B-fragments: tiles {w, w+8} for w<4, {w} for w>=4
    int t0 = w4 ? w : w;           // 0..3 (gate r) or 4..7 (gate z)
    int t1 = w + 8;                // 8..11 (gate n), only w<4
    bf16x8 Bfr0[8], Bfr1[8];
    {
        int ng0 = (t0 >> 2) * 256 + j * 64 + (t0 & 3) * 16 + lane16;
        const float* p0 = W_hh + (size_t)ng0 * 256 + quad * 8;
        #pragma unroll
        for (int kt = 0; kt < 8; ++kt) {
            const f32x4* q = (const f32x4*)(p0 + kt * 32);
            f32x4 u0 = q[0], u1 = q[1];
            bf16x8 v;
            v[0]=f2bf(u0[0]); v[1]=f2bf(u0[1]); v[2]=f2bf(u0[2]); v[3]=f2bf(u0[3]);
            v[4]=f2bf(u1[0]); v[5]=f2bf(u1[1]); v[6]=f2bf(u1[2]); v[7]=f2bf(u1[3]);
            Bfr0[kt] = v;
        }
        if (w4) {
            int ng1 = (t1 >> 2) * 256 + j * 64 + (t1 & 3) * 16 + lane16;
            const float* p1 = W_hh + (size_t)ng1 * 256 + quad * 8;
            #pragma unroll
            for (int kt = 0; kt < 8; ++kt) {
                const f32x4* q = (const f32x4*)(p1 + kt * 32);
                f32x4 u0 = q[0], u1 = q[1];
                bf16x8 v;
                v[0]=f2bf(u0[0]); v[1]=f2bf(u0[1]); v[2]=f2bf(u0[2]); v[3]=f2bf(u0[3]);
                v[4]=f2bf(u1[0]); v[5]=f2bf(u1[1]); v[6]=f2bf(u1[2]); v[7]=f2bf(u1[3]);
                Bfr1[kt] = v;
            }
        }
    }

    // ---- elementwise ownership: v = 2*tid, 2*tid+1 -> (b0, c0), (b0, c0+1)
    int b0 = tid >> 5, c0 = (tid & 31) * 2;
    int cg = j * 64 + c0;
    float bhr0 = b_hh[cg],       bhr1 = b_hh[cg + 1];
    float bhz0 = b_hh[256 + cg], bhz1 = b_hh[256 + cg + 1];
    float bhn0 = b_hh[512 + cg], bhn1 = b_hh[512 + cg + 1];
    float h0 = 0.f, h1 = 0.f;

    // ---- init LDS
    for (int v = tid; v < 4096; v += 512)
        h_all[(v >> 8) * 264 + (v & 255)] = 0;
    const uint32_t* gsl = (const uint32_t*)(gslice + (size_t)j * T_ * 3072);
    {   // prologue gate fill: steps 0..3 -> slots 0..3 (identity mapping)
        #pragma unroll
        for (int i = 0; i < 12; ++i)
            ((uint32_t*)gxr)[tid + i * 512] = gsl[tid + i * 512];
    }
    __syncthreads();

    f32x4 acc0 = {0.f,0.f,0.f,0.f}, acc1 = {0.f,0.f,0.f,0.f};

#define DO_KT(kt) { \
    bf16x8 a_ = *(const bf16x8*)&h_all[lane16 * 264 + (kt) * 32 + quad * 8]; \
    acc0 = __builtin_amdgcn_mfma_f32_16x16x32_bf16(a_, Bfr0[kt], acc0, 0, 0, 0); \
    if (w4) acc1 = __builtin_amdgcn_mfma_f32_16x16x32_bf16(a_, Bfr1[kt], acc1, 0, 0, 0); }

    for (int s = 0; s < T_; ++s) {
        // gate prefetch issue (steps s+1..s+4 -> slots 0..3, s%4==3)
        uint32_t pf[12];
        bool pfs = ((s & 3) == 3) && (s + 4 < T_);
        if (pfs) {
            const uint32_t* src = gsl + (size_t)(s + 1) * 1536;
            #pragma unroll
            for (int i = 0; i < 12; ++i) pf[i] = src[tid + i * 512];
        }

        // phase B: 6 non-own K-tiles (own 2 done last iteration, overlapped)
        #pragma unroll
        for (int kt = 0; kt < 8; ++kt)
            if ((kt >> 1) != j) DO_KT(kt);

        // write gh slice (D: col=lane16 -> n, row=quad*4+r -> batch)
        #pragma unroll
        for (int r = 0; r < 4; ++r) {
            gh_s[(quad * 4 + r) * 193 + t0 * 16 + lane16] = acc0[r];
            if (w4) gh_s[(quad * 4 + r) * 193 + t1 * 16 + lane16] = acc1[r];
        }
        __syncthreads();   // b1

        // elementwise: 2 h-values per thread
        uint32_t pi = (s + 1) & 1;
        {
            const short* gx = &gxr[(s & 3) * 3072 + b0 * 192];
            const float* gh = &gh_s[b0 * 193];
            float r0 = fast_sigmoid(bf2f(gx[c0])      + gh[c0]       + bhr0);
            float r1 = fast_sigmoid(bf2f(gx[c0 + 1])  + gh[c0 + 1]   + bhr1);
            float z0 = fast_sigmoid(bf2f(gx[64 + c0]) + gh[64 + c0]  + bhz0);
            float z1 = fast_sigmoid(bf2f(gx[65 + c0]) + gh[65 + c0]  + bhz1);
            float n0 = fast_tanh(bf2f(gx[128 + c0]) + r0 * (gh[128 + c0] + bhn0));
            float n1 = fast_tanh(bf2f(gx[129 + c0]) + r1 * (gh[129 + c0] + bhn1));
            h0 = (1.f - z0) * n0 + z0 * h0;
            h1 = (1.f - z1) * n1 + z1 * h1;
            uint32_t hv = (uint32_t)(uint16_t)f2bf(h0) |
                          ((uint32_t)(uint16_t)f2bf(h1) << 16);
            // own chunk to global (agent-visible), early so ack overlaps rest
            __hip_atomic_store(Hx + (pi * 4 + j) * 512 + tid, hv,
                               __ATOMIC_RELAXED, __HIP_MEMORY_SCOPE_AGENT);
            *(uint32_t*)&h_all[b0 * 264 + j * 64 + c0] = hv;
            float2 hv2; hv2.x = h0; hv2.y = h1;
            *(float2*)&ob[(s & 3) * 1024 + 2 * tid] = hv2;
        }
        __syncthreads();   // b2 (drains Hx stores wave-by-wave)

        // out flush: once per 4 steps, coalesced
        if ((s & 3) == 3) {
            int bA = tid >> 6, c = tid & 63;
            #pragma unroll
            for (int k = 0; k < 4; ++k) {
                size_t so = (size_t)(s - 3 + k) * 256 + j * 64 + c;
                out[(size_t)bA * (T_ * 256) + so]       = ob[k * 1024 + tid];
                out[(size_t)(bA + 8) * (T_ * 256) + so] = ob[k * 1024 + 512 + tid];
            }
        }

        if (s + 1 < T_) {
            if (tid == 0)
                __hip_atomic_store(&prog[j * 32], s + 1,
                                   __ATOMIC_RELEASE, __HIP_MEMORY_SCOPE_AGENT);
            // wave 7 spins for the 3 remote flags (capped: no infinite hang)
            if (w == 7 && l < 3) {
                int x = (j + 1 + (int)l) & 3;
                int it = 0, v;
                do {
                    v = __hip_atomic_load(&prog[x * 32],
                                          __ATOMIC_ACQUIRE, __HIP_MEMORY_SCOPE_AGENT);
                } while (v <= s && ++it < 8192);
            }
            // phase A of step s+1 (own 2 K-tiles) overlaps the spin
            acc0 = (f32x4){0.f,0.f,0.f,0.f};
            acc1 = (f32x4){0.f,0.f,0.f,0.f};
            #pragma unroll
            for (int kt = 0; kt < 8; ++kt)
                if ((kt >> 1) == j) DO_KT(kt);
            __syncthreads();   // b3

            // fetch 3 remote chunks (relaxed agent = cache-bypassing) -> h_all
            uint32_t d[3];
            #pragma unroll
            for (int i = 0; i < 3; ++i) {
                int x = (j + 1 + i) & 3;
                d[i] = __hip_atomic_load(Hx + (pi * 4 + x) * 512 + tid,
                                         __ATOMIC_RELAXED, __HIP_MEMORY_SCOPE_AGENT);
            }
            #pragma unroll
            for (int i = 0; i < 3; ++i) {
                int x = (j + 1 + i) & 3;
                *(uint32_t*)&h_all[b0 * 264 + x * 64 + c0] = d[i];
            }
        }

        if (pfs) {
            #pragma unroll
            for (int i = 0; i < 12; ++i)
                ((uint32_t*)gxr)[tid + i * 512] = pf[i];
        }
        __syncthreads();   // b4
    }
#undef DO_KT
}

// ---------------------------------------------------------------------------
extern "C" void kernel_launch(void* const* d_in, const int* in_sizes, int n_in,
                              void* d_out, int out_size, void* d_ws, size_t ws_size,
                              hipStream_t stream) {
    const float* feat  = (const float*)d_in[0];
    const float* W1    = (const float*)d_in[1];
    const float* b1    = (const float*)d_in[2];
    const float* W2    = (const float*)d_in[3];
    const float* b2    = (const float*)d_in[4];
    const float* Wt    = (const float*)d_in[5];
    const float* bt    = (const float*)d_in[6];
    const float* Wih_f = (const float*)d_in[7];
    const float* Whh   = (const float*)d_in[8];
    const float* bih   = (const float*)d_in[9];
    const float* bhh   = (const float*)d_in[10];
    float* out = (float*)d_out;

    // ws layout (135.4 MB total, same as before):
    //   [0, 33.5M)      c3 bf16; c1 aliases first 8.4M (dead after k2);
    //                   Hx[2][4][1024 shorts] (16KB) + prog (512B) alias the
    //                   front AFTER k3b (zeroed by k_zero, used only by k4)
    //   [33.5M, 134.2M) gslice bf16 (y2 aliases first 8.4M, dead after k3a)
    //   [134.2M, ...)   W2t / Wtt / Wih bf16
    char* ws = (char*)d_ws;
    short* c3    = (short*)(ws);
    short* c1    = (short*)(ws);
    uint32_t* Hx = (uint32_t*)(ws);                 // [0, 16384)
    int* prog    = (int*)(ws + 16384);              // 128 ints
    short* gslice= (short*)(ws + 33554432);
    short* y2    = (short*)(ws + 33554432);
    short* W2t   = (short*)(ws + 134217728);
    short* Wtt   = (short*)(ws + 134217728 + 262144);
    short* Wih   = (short*)(ws + 134217728 + 262144 + 524288);

    k1_conv1 <<<16384, 256, 0, stream>>>(feat, W1, b1, c1);
    k_prep   <<<1024, 256, 0, stream>>>(W2, Wt, Wih_f, W2t, Wtt, Wih);
    k2_conv2 <<<256,  256, 0, stream>>>(c1, W2t, b2, y2);
    k3a_tconv<<<1024, 256, 0, stream>>>(y2, Wtt, bt, c3);      // kills c1
    k3b_xproj<<<4096, 256, 0, stream>>>(c3, Wih, bih, gslice); // kills y2
    k_zero   <<<1,    128, 0, stream>>>(prog);                 // c3 dead now
    k4_gru_x4<<<4,    512, 0, stream>>>(Whh, bhh, gslice, out, Hx, prog);
}

// Round 4
// 5223.098 us; speedup vs baseline: 2.0028x; 2.0028x over previous
//
#include <hip/hip_runtime.h>
#include <hip/hip_bf16.h>
#include <stdint.h>

// Problem dims
#define B_   16
#define T_   4096
#define F_   47
#define HID_ 64
#define CH_  256
#define TG_  1024   // T/4
#define G3_  768    // 3*CH

using bf16x8 = __attribute__((ext_vector_type(8))) short;  // 8 bf16 (4 VGPRs)
using f32x4  = __attribute__((ext_vector_type(4))) float;  // 4 fp32 acc
using f16x8  = __attribute__((ext_vector_type(8))) _Float16;
using h2     = __attribute__((ext_vector_type(2))) _Float16;

__device__ __forceinline__ short f2bf(float f) {
    union { float f; uint32_t u; } v; v.f = f;
    uint32_t u = v.u;
    uint32_t r = (u + 0x7fffu + ((u >> 16) & 1u)) >> 16;   // RNE
    return (short)r;
}
__device__ __forceinline__ float bf2f(short s) {
    union { uint32_t u; float f; } v; v.u = ((uint32_t)(uint16_t)s) << 16;
    return v.f;
}
__device__ __forceinline__ float fast_tanh(float x) {
    float e = __expf(2.f * x);           // inf-safe
    return 1.f - 2.f / (e + 1.f);
}
__device__ __forceinline__ float fast_sigmoid(float x) {
    return 1.f / (1.f + __expf(-x));
}

#if __has_builtin(__builtin_amdgcn_fdot2)
#define FDOT2(a, b, c) __builtin_amdgcn_fdot2((a), (b), (c), false)
#else
__device__ __forceinline__ float fdot2_emul(h2 a, h2 b, float c) {
    return c + (float)a[0] * (float)b[0] + (float)a[1] * (float)b[1];
}
#define FDOT2(a, b, c) fdot2_emul((a), (b), (c))
#endif

#if __has_builtin(__builtin_amdgcn_global_load_lds)
#define HAS_GLL 1
__device__ __forceinline__ void gl_lds16(const void* g, void* l) {
    __builtin_amdgcn_global_load_lds(
        (const __attribute__((address_space(1))) uint32_t*)g,
        (__attribute__((address_space(3))) uint32_t*)l, 16, 0, 0);
}
#else
#define HAS_GLL 0
#endif

// ---------------------------------------------------------------------------
// K1: conv1 (pointwise 47->64) + tanh, fp32 VALU, writes c1 as bf16
__global__ __launch_bounds__(256) void k1_conv1(const float* __restrict__ feat,
        const float* __restrict__ W1, const float* __restrict__ b1,
        short* __restrict__ c1) {
    __shared__ float sW[47 * 64];
    __shared__ float sF[4 * 47];
    int tid = threadIdx.x;
    int b = blockIdx.x >> 10, t0 = (blockIdx.x & 1023) * 4;
    if (tid < 188) sF[tid] = feat[((size_t)b * T_ + t0) * 47 + tid];
    for (int i = tid; i < 47 * 64; i += 256) {
        int f = i >> 6, h = i & 63;
        sW[i] = W1[h * 47 + f];
    }
    __syncthreads();
    int fr = tid >> 6, h = tid & 63;
    float acc = b1[h];
    #pragma unroll
    for (int f = 0; f < 47; ++f)
        acc += sF[fr * 47 + f] * sW[f * 64 + h];
    c1[((size_t)b * T_ + t0 + fr) * 64 + h] = f2bf(fast_tanh(acc));
}

// ---------------------------------------------------------------------------
// Weight prep (bf16 B^T layouts for the prelude GEMMs)
__global__ __launch_bounds__(256) void k_prep(const float* __restrict__ W2,
        const float* __restrict__ Wt, const float* __restrict__ Wih_f,
        short* __restrict__ W2t, short* __restrict__ Wtt, short* __restrict__ Wih) {
    int idx = blockIdx.x * 256 + threadIdx.x;
    if (idx < 256 * 512) {
        int o = idx >> 9, i = idx & 511, d = i >> 8, jj = i & 255;
        W2t[idx] = f2bf(W2[(size_t)o * 512 + jj * 2 + d]);
    }
    {
        int n = idx >> 8, ic = idx & 255, o = n & 255, kp = n >> 8;
        Wtt[idx] = f2bf(Wt[(size_t)ic * 1024 + o * 4 + kp]);
    }
    if (idx < G3_ * CH_)
        Wih[idx] = f2bf(Wih_f[idx]);
}

// ---------------------------------------------------------------------------
// K2: conv2 (k=2 causal) as GEMM M=16384,K=512,N=256 + tanh.
__global__ __launch_bounds__(256) void k2_conv2(const short* __restrict__ c1,
        const short* __restrict__ W2t, const float* __restrict__ b2,
        short* __restrict__ y2) {
    int tid = threadIdx.x, w = tid >> 6, l = tid & 63;
    int lane16 = l & 15, quad = l >> 4;
    int mt = blockIdx.x * 4 + w;
    int row = mt * 16 + lane16;
    int tg = row & 1023;
    const short* Arow = c1 + (size_t)row * 256 - 256;
    bf16x8 zero8 = {0,0,0,0,0,0,0,0};
    bf16x8 af[16];
    #pragma unroll
    for (int kt = 0; kt < 16; ++kt) {
        int i0 = kt * 32 + quad * 8;
        bool masked = (tg == 0) && (kt < 8);
        const short* p = masked ? c1 : (Arow + i0);
        bf16x8 v = *(const bf16x8*)p;
        af[kt] = masked ? zero8 : v;
    }
    #pragma unroll
    for (int nt = 0; nt < 16; ++nt) {
        int n = nt * 16 + lane16;
        f32x4 acc = {0.f, 0.f, 0.f, 0.f};
        const short* Brow = W2t + (size_t)n * 512 + quad * 8;
        #pragma unroll
        for (int kt = 0; kt < 16; ++kt) {
            bf16x8 bf = *(const bf16x8*)(Brow + kt * 32);
            acc = __builtin_amdgcn_mfma_f32_16x16x32_bf16(af[kt], bf, acc, 0, 0, 0);
        }
        float bias = b2[n];
        #pragma unroll
        for (int r = 0; r < 4; ++r) {
            int mrow = mt * 16 + quad * 4 + r;
            y2[(size_t)mrow * 256 + n] = f2bf(fast_tanh(acc[r] + bias));
        }
    }
}

// ---------------------------------------------------------------------------
// K3a: tconv as GEMM M=16384,K=256,N=1024 + tanh -> c3 bf16.
__global__ __launch_bounds__(256) void k3a_tconv(const short* __restrict__ y2,
        const short* __restrict__ Wtt, const float* __restrict__ bt,
        short* __restrict__ c3) {
    int tid = threadIdx.x, w = tid >> 6, l = tid & 63;
    int lane16 = l & 15, quad = l >> 4;
    int mt = blockIdx.x;
    int row = mt * 16 + lane16;
    const short* Arow = y2 + (size_t)row * 256 + quad * 8;
    bf16x8 af[8];
    #pragma unroll
    for (int kt = 0; kt < 8; ++kt) af[kt] = *(const bf16x8*)(Arow + kt * 32);
    #pragma unroll
    for (int nt2 = 0; nt2 < 16; ++nt2) {
        int n = (w * 16 + nt2) * 16 + lane16;
        f32x4 acc = {0.f, 0.f, 0.f, 0.f};
        const short* Brow = Wtt + (size_t)n * 256 + quad * 8;
        #pragma unroll
        for (int kt = 0; kt < 8; ++kt) {
            bf16x8 bf = *(const bf16x8*)(Brow + kt * 32);
            acc = __builtin_amdgcn_mfma_f32_16x16x32_bf16(af[kt], bf, acc, 0, 0, 0);
        }
        int kp = n >> 8, o = n & 255;
        float bias = bt[o];
        #pragma unroll
        for (int r = 0; r < 4; ++r) {
            int mrow = mt * 16 + quad * 4 + r;
            int bb = mrow >> 10, tgg = mrow & 1023;
            c3[(((size_t)bb * TG_ + tgg) * 4 + kp) * 256 + o] =
                f2bf(fast_tanh(acc[r] + bias));
        }
    }
}

// ---------------------------------------------------------------------------
// K3b: x-projection GEMM M=65536,K=256,N=768 (+b_ih) -> gates bf16.
// gates[(b*T+t)*768 + n]
__global__ __launch_bounds__(256) void k3b_xproj(const short* __restrict__ c3,
        const short* __restrict__ Wih, const float* __restrict__ b_ih,
        short* __restrict__ gates) {
    int tid = threadIdx.x, w = tid >> 6, l = tid & 63;
    int lane16 = l & 15, quad = l >> 4;
    int mt = blockIdx.x;
    int row = mt * 16 + lane16;
    const short* Arow = c3 + (size_t)row * 256 + quad * 8;
    bf16x8 af[8];
    #pragma unroll
    for (int kt = 0; kt < 8; ++kt) af[kt] = *(const bf16x8*)(Arow + kt * 32);
    #pragma unroll
    for (int nt2 = 0; nt2 < 12; ++nt2) {
        int n = (w * 12 + nt2) * 16 + lane16;
        f32x4 acc = {0.f, 0.f, 0.f, 0.f};
        const short* Brow = Wih + (size_t)n * 256 + quad * 8;
        #pragma unroll
        for (int kt = 0; kt < 8; ++kt) {
            bf16x8 bf = *(const bf16x8*)(Brow + kt * 32);
            acc = __builtin_amdgcn_mfma_f32_16x16x32_bf16(af[kt], bf, acc, 0, 0, 0);
        }
        float bias = b_ih[n];
        #pragma unroll
        for (int r = 0; r < 4; ++r) {
            int mrow = mt * 16 + quad * 4 + r;
            gates[(size_t)mrow * G3_ + n] = f2bf(acc[r] + bias);
        }
    }
}

// ---------------------------------------------------------------------------
// K4: persistent GRU via VALU v_dot2_f32_f16 — 1 block per batch, 512 thr.
// W_hh lives in registers as f16 pairs: thread (q=tid&3, n0=tid>>2) owns
// outputs {n0+128k, k<6} over K-quarter q => wreg[6][32] h2 = 192 VGPRs.
// Per step: 192 fdot2/thread (768 issue cyc/SIMD = 2.4x effective MFMA rate
// for this matvec), 4-way partial reduce via LDS, ew on threads<256.
// Gates stream 8 steps at a time via global_load_lds (zero VGPR).
__global__ __launch_bounds__(512) void k4_gru_dot2(const float* __restrict__ W_hh,
        const float* __restrict__ b_hh, const short* __restrict__ gates,
        float* __restrict__ out) {
    __shared__ __align__(16) short gxb[2][8][G3_];   // 24KB gate ring (bf16)
    __shared__ __align__(16) float part[G3_ * 4];    // 12KB partials [n][q]
    __shared__ __align__(16) float ob[8 * 256];      // 8KB out staging
    __shared__ __align__(16) short hq_s[4 * 72];     // h as f16, padded quarters

    int tid = threadIdx.x, l = tid & 63, w = tid >> 6;
    int q = tid & 3, n0 = tid >> 2;                  // n0 in 0..127
    int b = blockIdx.x;

    // ---- W_hh -> f16-pair registers (one-time; fp32 source)
    h2 wreg[6][32];
    #pragma unroll
    for (int k = 0; k < 6; ++k) {
        const float2* row = (const float2*)(W_hh + ((size_t)(n0 + k * 128)) * 256 + q * 64);
        #pragma unroll
        for (int j = 0; j < 32; ++j) {
            float2 v = row[j];
            h2 p; p[0] = (_Float16)v.x; p[1] = (_Float16)v.y;
            wreg[k][j] = p;
        }
    }

    float h_reg = 0.f, bhr = 0.f, bhz = 0.f, bhn = 0.f;
    if (tid < 256) {
        bhr = b_hh[tid]; bhz = b_hh[256 + tid]; bhn = b_hh[512 + tid];
    }
    if (tid < 288) hq_s[tid] = 0;                    // h = 0 (f16)

    const short* gbase = gates + (size_t)b * T_ * G3_;
    const char* gbytes = (const char*)gbase;

    // prologue: steps 0..7 -> ring half 0
#if HAS_GLL
    {
        char* dst = (char*)&gxb[0][0][0];
        gl_lds16(gbytes + w * 1024 + l * 16, dst + w * 1024);
        if (w < 4) gl_lds16(gbytes + (8 + w) * 1024 + l * 16, dst + (8 + w) * 1024);
    }
#else
    {
        const uint32_t* g32 = (const uint32_t*)gbytes;
        uint32_t* d = (uint32_t*)&gxb[0][0][0];
        #pragma unroll
        for (int i = 0; i < 6; ++i) d[tid + i * 512] = g32[tid + i * 512];
    }
#endif
    __syncthreads();

    float* outb = out + (size_t)b * T_ * CH_;
    for (int s = 0; s < T_; ++s) {
        bool grp0 = ((s & 7) == 0) && (s + 8 < T_);
#if HAS_GLL
        if (grp0) {   // async stage next 8 steps into the other ring half
            const char* src = gbytes + (size_t)(s + 8) * 1536;
            char* dst = (char*)&gxb[((s >> 3) + 1) & 1][0][0];
            gl_lds16(src + w * 1024 + l * 16, dst + w * 1024);
            if (w < 4) gl_lds16(src + (8 + w) * 1024 + l * 16, dst + (8 + w) * 1024);
        }
#else
        uint32_t pf[6];
        if (grp0) {
            const uint32_t* src = (const uint32_t*)(gbytes + (size_t)(s + 8) * 1536);
            #pragma unroll
            for (int i = 0; i < 6; ++i) pf[i] = src[tid + i * 512];
        }
#endif

        // ---- dot2 phase: h-quarter from LDS (conflict-free padded), 192 fdot2
        h2 hq[32];
        #pragma unroll
        for (int g2 = 0; g2 < 8; ++g2) {
            f16x8 v = *(const f16x8*)&hq_s[q * 72 + g2 * 8];
            #pragma unroll
            for (int p2 = 0; p2 < 4; ++p2) {
                h2 p; p[0] = v[p2 * 2]; p[1] = v[p2 * 2 + 1];
                hq[g2 * 4 + p2] = p;
            }
        }
        float acc[6] = {0.f, 0.f, 0.f, 0.f, 0.f, 0.f};
        #pragma unroll
        for (int j = 0; j < 32; ++j) {
            #pragma unroll
            for (int k = 0; k < 6; ++k)
                acc[k] = FDOT2(wreg[k][j], hq[j], acc[k]);
        }
        #pragma unroll
        for (int k = 0; k < 6; ++k)
            part[(n0 + k * 128) * 4 + q] = acc[k];
        __syncthreads();   // b1

#if !HAS_GLL
        if (grp0) {
            uint32_t* d = (uint32_t*)&gxb[((s >> 3) + 1) & 1][0][0];
            #pragma unroll
            for (int i = 0; i < 6; ++i) d[tid + i * 512] = pf[i];
        }
#endif
        // ---- elementwise on threads < 256 (one wave per SIMD)
        if (tid < 256) {
            const short* gx = &gxb[(s >> 3) & 1][s & 7][0];
            f32x4 pr = *(const f32x4*)&part[tid * 4];
            f32x4 pz = *(const f32x4*)&part[(256 + tid) * 4];
            f32x4 pn = *(const f32x4*)&part[(512 + tid) * 4];
            float gr = (pr[0] + pr[1]) + (pr[2] + pr[3]);
            float gz = (pz[0] + pz[1]) + (pz[2] + pz[3]);
            float gn = (pn[0] + pn[1]) + (pn[2] + pn[3]);
            float xr = bf2f(gx[tid]), xz = bf2f(gx[256 + tid]), xn = bf2f(gx[512 + tid]);
            float r = fast_sigmoid(xr + gr + bhr);
            float z = fast_sigmoid(xz + gz + bhz);
            float nn = fast_tanh(xn + r * (gn + bhn));
            h_reg = (1.f - z) * nn + z * h_reg;
            union { _Float16 f; short u; } cv; cv.f = (_Float16)h_reg;
            hq_s[(tid >> 6) * 72 + (tid & 63)] = cv.u;
            ob[(s & 7) * 256 + tid] = h_reg;
        }
        __syncthreads();   // b2

        // ---- out flush once per 8 steps, coalesced f32x4
        if ((s & 7) == 7) {
            f32x4 v = *(const f32x4*)&ob[tid * 4];
            *(f32x4*)&outb[(size_t)(s - 7 + (tid >> 6)) * 256 + (tid & 63) * 4] = v;
        }
    }
}

// ---------------------------------------------------------------------------
extern "C" void kernel_launch(void* const* d_in, const int* in_sizes, int n_in,
                              void* d_out, int out_size, void* d_ws, size_t ws_size,
                              hipStream_t stream) {
    const float* feat  = (const float*)d_in[0];
    const float* W1    = (const float*)d_in[1];
    const float* b1    = (const float*)d_in[2];
    const float* W2    = (const float*)d_in[3];
    const float* b2    = (const float*)d_in[4];
    const float* Wt    = (const float*)d_in[5];
    const float* bt    = (const float*)d_in[6];
    const float* Wih_f = (const float*)d_in[7];
    const float* Whh   = (const float*)d_in[8];
    const float* bih   = (const float*)d_in[9];
    const float* bhh   = (const float*)d_in[10];
    float* out = (float*)d_out;

    // ws layout (135.4 MB):
    //   [0, 33.5M)      c3 bf16 (c1 aliases first 8.4M; c1 dead after K2)
    //   [33.5M, 134.2M) gates bf16 (y2 aliases first 8.4M; y2 dead after K3a)
    //   [134.2M, ...)   W2t / Wtt / Wih bf16
    char* ws = (char*)d_ws;
    short* c3    = (short*)(ws);
    short* c1    = (short*)(ws);
    short* gates = (short*)(ws + 33554432);
    short* y2    = (short*)(ws + 33554432);
    short* W2t   = (short*)(ws + 134217728);
    short* Wtt   = (short*)(ws + 134217728 + 262144);
    short* Wih   = (short*)(ws + 134217728 + 262144 + 524288);

    k1_conv1   <<<16384, 256, 0, stream>>>(feat, W1, b1, c1);
    k_prep     <<<1024, 256, 0, stream>>>(W2, Wt, Wih_f, W2t, Wtt, Wih);
    k2_conv2   <<<256,  256, 0, stream>>>(c1, W2t, b2, y2);
    k3a_tconv  <<<1024, 256, 0, stream>>>(y2, Wtt, bt, c3);      // kills c1
    k3b_xproj  <<<4096, 256, 0, stream>>>(c3, Wih, bih, gates);  // kills y2
    k4_gru_dot2<<<16,   512, 0, stream>>>(Whh, bhh, gates, out);
}